// Round 3
// baseline (741.231 us; speedup 1.0000x reference)
//
#include <hip/hip_runtime.h>
#include <hip/hip_bf16.h>
#include <stdint.h>
#include <float.h>

// VQ quantize: z[65536,256] f32, weight[1024,256] f32.
// ref (numpy fp32): d = fl32(fl32(A - 2*B) + C), A=|z|^2 (pairwise sum),
// B = z.wT (sgemm), C=|w|^2; idx = argmax(-d) (first-index ties).
// Outputs (float32, concatenated): quantized [65536*256], indices [65536].
//
// Screen: fp32 VALU GEMM argmin with margin; ambiguous rows (margin < TAU)
// re-decided by bit-exact simulation of the numpy arithmetic:
//   A,C: numpy pairwise order (two 128-blocks, 8 accumulators, fixed tree),
//        products rounded before adds (__fmul_rn/__fadd_rn, no contraction)
//   B:   sequential fp32 fma chain over ascending k (OpenBLAS microkernel order)

constexpr int NROWS = 65536;
constexpr int D     = 256;
constexpr int CODES = 1024;

constexpr int TM = 64;          // rows per main block
constexpr int TN = 256;         // codes per chunk
constexpr int KB = 8;           // k-slab in LDS
constexpr int WSTR = TN + 4;
constexpr int ZSTR = TM + 4;
constexpr float TAU = 1.2e-4f;  // > 2*(ulp(512)) + screen error; covers quantization

constexpr int RB = 8;           // rows per refine batch
constexpr int CC = 32;          // codes per refine chunk
constexpr int LSTR = 260;       // LDS row stride (floats) in refine

// ws layout (bytes): idx[0,256K) | flagged[256K,512K) | cnt@512K | C@525312(4K)

__global__ void init_ws(int* cnt) { if (threadIdx.x == 0) *cnt = 0; }

// exact numpy pairwise sum of squares of a[0..255] (fp32, no contraction)
__device__ __forceinline__ float np_pairwise_sq256(const float* a) {
    float res[2];
    #pragma unroll
    for (int b = 0; b < 2; ++b) {
        float r[8];
        #pragma unroll
        for (int j = 0; j < 8; ++j) r[j] = 0.f;
        #pragma unroll
        for (int m = 0; m < 16; ++m) {
            const int base = b * 128 + m * 8;
            #pragma unroll
            for (int j = 0; j < 8; ++j)
                r[j] = __fadd_rn(r[j], __fmul_rn(a[base + j], a[base + j]));
        }
        res[b] = __fadd_rn(__fadd_rn(__fadd_rn(r[0], r[1]), __fadd_rn(r[2], r[3])),
                           __fadd_rn(__fadd_rn(r[4], r[5]), __fadd_rn(r[6], r[7])));
    }
    return __fadd_rn(res[0], res[1]);
}

__global__ __launch_bounds__(256) void rownorm_np(const float* __restrict__ x,
                                                  float* __restrict__ out, int nrows) {
    const int row = blockIdx.x * 256 + threadIdx.x;
    if (row >= nrows) return;
    float a[256];
    const float4* p = (const float4*)(x + (size_t)row * D);
    #pragma unroll
    for (int k4 = 0; k4 < 64; ++k4) {
        float4 v = p[k4];
        a[k4 * 4 + 0] = v.x; a[k4 * 4 + 1] = v.y;
        a[k4 * 4 + 2] = v.z; a[k4 * 4 + 3] = v.w;
    }
    out[row] = np_pairwise_sq256(a);
}

__global__ __launch_bounds__(256) void vq_main(const float* __restrict__ z,
                                               const float* __restrict__ w,
                                               const float* __restrict__ Cn,
                                               int* __restrict__ idx_out,
                                               int* __restrict__ flagged,
                                               int* __restrict__ cnt) {
    __shared__ float wt[KB][WSTR];   // [k][code]
    __shared__ float zt[KB][ZSTR];   // [k][row]

    const int t    = threadIdx.x;
    const int tx   = t & 31;
    const int ty   = t >> 5;
    const int row0 = blockIdx.x * TM;

    float rm1[8], rm2[8];
    int   ri1[8];
    #pragma unroll
    for (int i = 0; i < 8; ++i) { rm1[i] = FLT_MAX; rm2[i] = FLT_MAX; ri1[i] = 0; }

    for (int cc = 0; cc < CODES / TN; ++cc) {
        const int c0 = cc * TN;
        float acc[8][8];
        #pragma unroll
        for (int i = 0; i < 8; ++i)
            #pragma unroll
            for (int j = 0; j < 8; ++j) acc[i][j] = 0.f;

        for (int ks = 0; ks < D / KB; ++ks) {
            const int k0 = ks * KB;
            {
                const float4* gp = (const float4*)(w + (size_t)(c0 + t) * D + k0);
                float4 a = gp[0], b = gp[1];
                wt[0][t] = a.x; wt[1][t] = a.y; wt[2][t] = a.z; wt[3][t] = a.w;
                wt[4][t] = b.x; wt[5][t] = b.y; wt[6][t] = b.z; wt[7][t] = b.w;
            }
            {
                const int r = t >> 2, q = t & 3;
                const float2* gp = (const float2*)(z + (size_t)(row0 + r) * D + k0 + q * 2);
                float2 a = gp[0];
                zt[q * 2 + 0][r] = a.x;
                zt[q * 2 + 1][r] = a.y;
            }
            __syncthreads();
            #pragma unroll
            for (int k = 0; k < KB; ++k) {
                float4 za = *(const float4*)&zt[k][ty * 8];
                float4 zb = *(const float4*)&zt[k][ty * 8 + 4];
                float4 wa = *(const float4*)&wt[k][tx * 8];
                float4 wb = *(const float4*)&wt[k][tx * 8 + 4];
                float zr[8] = {za.x, za.y, za.z, za.w, zb.x, zb.y, zb.z, zb.w};
                float wr[8] = {wa.x, wa.y, wa.z, wa.w, wb.x, wb.y, wb.z, wb.w};
                #pragma unroll
                for (int i = 0; i < 8; ++i)
                    #pragma unroll
                    for (int j = 0; j < 8; ++j)
                        acc[i][j] = fmaf(zr[i], wr[j], acc[i][j]);
            }
            __syncthreads();
        }
        #pragma unroll
        for (int j = 0; j < 8; ++j) {
            const int gc = c0 + tx * 8 + j;
            const float cj = Cn[gc];
            #pragma unroll
            for (int i = 0; i < 8; ++i) {
                float v = fmaf(-2.f, acc[i][j], cj);
                if (v < rm1[i]) { rm2[i] = rm1[i]; rm1[i] = v; ri1[i] = gc; }
                else if (v < rm2[i]) rm2[i] = v;
            }
        }
    }

    #pragma unroll
    for (int i = 0; i < 8; ++i) {
        float m1 = rm1[i], m2 = rm2[i];
        int   i1 = ri1[i];
        #pragma unroll
        for (int off = 16; off; off >>= 1) {
            float om1 = __shfl_xor(m1, off, 64);
            float om2 = __shfl_xor(m2, off, 64);
            int   oi1 = __shfl_xor(i1, off, 64);
            float nm2 = fminf(m2, om2);
            if (om1 < m1 || (om1 == m1 && oi1 < i1)) { nm2 = fminf(nm2, m1); m1 = om1; i1 = oi1; }
            else nm2 = fminf(nm2, om1);
            m2 = nm2;
        }
        if (tx == 0) {
            const int row = row0 + ty * 8 + i;
            idx_out[row] = i1;
            if (m2 - m1 < TAU) {
                int pos = atomicAdd(cnt, 1);
                flagged[pos] = row;
            }
        }
    }
}

// exact d_sim re-decision for flagged rows, RB rows per batch
__global__ __launch_bounds__(256) void vq_refine(const float* __restrict__ z,
                                                 const float* __restrict__ w,
                                                 const float* __restrict__ Cn,
                                                 const int* __restrict__ flagged,
                                                 const int* __restrict__ cnt,
                                                 int* __restrict__ idx_out) {
    __shared__ float zl[RB][LSTR];
    __shared__ float wl[CC][LSTR];
    __shared__ float sA[RB];
    __shared__ int   rowids[RB];
    __shared__ float bestd[256];
    __shared__ int   besti[256];

    const int t  = threadIdx.x;
    const int cw = t >> 3;   // code within chunk 0..31
    const int rw = t & 7;    // row within batch 0..7
    const int n  = *cnt;
    const int nbatch = (n + RB - 1) / RB;

    for (int batch = blockIdx.x; batch < nbatch; batch += gridDim.x) {
        __syncthreads();                       // protect LDS reuse across batches
        if (t < RB) {
            const int fi = batch * RB + t;
            rowids[t] = (fi < n) ? flagged[fi] : -1;
        }
        __syncthreads();
        for (int i = t; i < RB * 64; i += 256) {
            const int r = i >> 6, k4 = i & 63;
            const int row = rowids[r];
            float4 v = make_float4(0.f, 0.f, 0.f, 0.f);
            if (row >= 0) v = ((const float4*)(z + (size_t)row * D))[k4];
            *(float4*)&zl[r][k4 * 4] = v;
        }
        __syncthreads();
        if (t < RB) sA[t] = np_pairwise_sq256(zl[t]);   // exact numpy A

        float bd = FLT_MAX;
        int   bi = 0;
        for (int cc0 = 0; cc0 < CODES; cc0 += CC) {
            __syncthreads();                   // wl reuse safe; sA visible (1st iter)
            for (int i = t; i < CC * 64; i += 256) {
                const int c = i >> 6, k4 = i & 63;
                *(float4*)&wl[c][k4 * 4] = ((const float4*)(w + (size_t)(cc0 + c) * D))[k4];
            }
            __syncthreads();
            // B: sequential fp32 fma chain, ascending k (sgemm microkernel order)
            float B = 0.f;
            #pragma unroll 4
            for (int k4 = 0; k4 < 64; ++k4) {
                float4 zv = *(const float4*)&zl[rw][k4 * 4];
                float4 wv = *(const float4*)&wl[cw][k4 * 4];
                B = fmaf(zv.x, wv.x, B);
                B = fmaf(zv.y, wv.y, B);
                B = fmaf(zv.z, wv.z, B);
                B = fmaf(zv.w, wv.w, B);
            }
            const int code = cc0 + cw;
            const float tt = __fsub_rn(sA[rw], __fmul_rn(2.0f, B));
            const float d  = __fadd_rn(tt, Cn[code]);
            if (d < bd || (d == bd && code < bi)) { bd = d; bi = code; }
        }
        bestd[t] = bd; besti[t] = bi;
        __syncthreads();
        for (int off = 128; off >= 8; off >>= 1) {
            if (t < off) {
                const float od = bestd[t + off];
                const int   oi = besti[t + off];
                if (od < bestd[t] || (od == bestd[t] && oi < besti[t])) {
                    bestd[t] = od; besti[t] = oi;
                }
            }
            __syncthreads();
        }
        if (t < RB) {
            const int row = rowids[t];
            if (row >= 0) idx_out[row] = besti[t];
        }
    }
}

__global__ __launch_bounds__(256) void vq_gather(const float* __restrict__ w,
                                                 const int* __restrict__ idx,
                                                 float* __restrict__ outq,
                                                 float* __restrict__ outi) {
    const int row = blockIdx.x;
    const int t   = threadIdx.x;
    const int j   = idx[row];
    outq[(size_t)row * D + t] = w[(size_t)j * D + t];
    if (t == 0) outi[row] = (float)j;
}

extern "C" void kernel_launch(void* const* d_in, const int* in_sizes, int n_in,
                              void* d_out, int out_size, void* d_ws, size_t ws_size,
                              hipStream_t stream) {
    const float* z = (const float*)d_in[0];
    const float* w = (const float*)d_in[1];
    float* outq = (float*)d_out;
    float* outi = outq + (size_t)NROWS * D;

    char* ws      = (char*)d_ws;
    int*  idx     = (int*)ws;
    int*  flagged = (int*)(ws + 262144);
    int*  cnt     = (int*)(ws + 524288);
    float* Cn     = (float*)(ws + 525312);

    init_ws<<<1, 64, 0, stream>>>(cnt);
    rownorm_np<<<(CODES + 255) / 256, 256, 0, stream>>>(w, Cn, CODES);
    vq_main<<<NROWS / TM, 256, 0, stream>>>(z, w, Cn, idx, flagged, cnt);
    vq_refine<<<256, 256, 0, stream>>>(z, w, Cn, flagged, cnt, idx);
    vq_gather<<<NROWS, 256, 0, stream>>>(w, idx, outq, outi);
}

// Round 4
// 357.843 us; speedup vs baseline: 2.0714x; 2.0714x over previous
//
#include <hip/hip_runtime.h>
#include <hip/hip_bf16.h>
#include <stdint.h>
#include <float.h>

// VQ quantize: z[65536,256] f32, weight[1024,256] f32.
// ref (numpy fp32): d = fl32(fl32(A - 2*B) + C); idx = argmax(-d) (first-index ties).
// Outputs (float32, concat): quantized [65536*256], indices [65536].
//
// Pipeline:
//   1) to_bf16: z,w -> bf16 copies (scratch inside d_out; dead before gather)
//   2) rownorm_np: C=|w|^2 in exact numpy pairwise order
//   3) vq_screen: bf16 MFMA 16x16x32 GEMM (scores = C - 2*z.wT), per-row
//      (min1,min2,idx); rows with margin < TAU flagged. bf16 screen error
//      sigma~2e-5 on margins; TAU=2.5e-4 is ~12 sigma + sim-quantization.
//   4) vq_refine: flagged rows re-decided with bit-exact numpy-fp32 simulation
//      (pairwise A, sequential-k fma chain B) -- proven absmax=0 in round 3.
//   5) vq_gather.

constexpr int NROWS = 65536;
constexpr int D     = 256;
constexpr int CODES = 1024;

constexpr float TAU_SCREEN = 2.5e-4f;

typedef __attribute__((ext_vector_type(8))) short short8;   // 8 bf16 = 4 VGPR
typedef __attribute__((ext_vector_type(4))) float f32x4;

// ---------------- init ----------------
__global__ void init_ws(int* cnt) { if (threadIdx.x == 0) *cnt = 0; }

// ---------------- fp32 -> bf16 (RNE) ----------------
__device__ __forceinline__ unsigned short f2bf(float x) {
    union { __hip_bfloat16 h; unsigned short u; } c;
    c.h = __float2bfloat16(x);
    return c.u;
}

__global__ __launch_bounds__(256) void to_bf16(const float* __restrict__ src,
                                               unsigned short* __restrict__ dst,
                                               int n8) {
    const int i = blockIdx.x * 256 + threadIdx.x;
    if (i >= n8) return;
    const float4* s = (const float4*)src + (size_t)i * 2;
    float4 a = s[0], b = s[1];
    union { unsigned short u[8]; uint4 v; } p;
    p.u[0] = f2bf(a.x); p.u[1] = f2bf(a.y); p.u[2] = f2bf(a.z); p.u[3] = f2bf(a.w);
    p.u[4] = f2bf(b.x); p.u[5] = f2bf(b.y); p.u[6] = f2bf(b.z); p.u[7] = f2bf(b.w);
    *(uint4*)(dst + (size_t)i * 8) = p.v;
}

// ---------------- exact numpy pairwise |row|^2 ----------------
__device__ __forceinline__ float np_pairwise_sq256(const float* a) {
    float res[2];
    #pragma unroll
    for (int b = 0; b < 2; ++b) {
        float r[8];
        #pragma unroll
        for (int j = 0; j < 8; ++j) r[j] = 0.f;
        #pragma unroll
        for (int m = 0; m < 16; ++m) {
            const int base = b * 128 + m * 8;
            #pragma unroll
            for (int j = 0; j < 8; ++j)
                r[j] = __fadd_rn(r[j], __fmul_rn(a[base + j], a[base + j]));
        }
        res[b] = __fadd_rn(__fadd_rn(__fadd_rn(r[0], r[1]), __fadd_rn(r[2], r[3])),
                           __fadd_rn(__fadd_rn(r[4], r[5]), __fadd_rn(r[6], r[7])));
    }
    return __fadd_rn(res[0], res[1]);
}

__global__ __launch_bounds__(256) void rownorm_np(const float* __restrict__ x,
                                                  float* __restrict__ out, int nrows) {
    const int row = blockIdx.x * 256 + threadIdx.x;
    if (row >= nrows) return;
    float a[256];
    const float4* p = (const float4*)(x + (size_t)row * D);
    #pragma unroll
    for (int k4 = 0; k4 < 64; ++k4) {
        float4 v = p[k4];
        a[k4 * 4 + 0] = v.x; a[k4 * 4 + 1] = v.y;
        a[k4 * 4 + 2] = v.z; a[k4 * 4 + 3] = v.w;
    }
    out[row] = np_pairwise_sq256(a);
}

// ---------------- bf16 MFMA screen ----------------
// block = 128 rows x all 1024 codes (8 n-blocks looped), 4 waves (2x2),
// each wave 64x64 via 4x4 tiles of mfma_f32_16x16x32_bf16.
// LDS tiles [row][64k] bf16, 16B chunks XOR-swizzled by (row&7) -> conflict-free
// b128 fragment reads. Frag layouts (m89/m91-verified):
//   A: lane l holds A[m=l&15][k=(l>>4)*8+j]; B (from W row-major [code][k]) same;
//   D: row=(l>>4)*4+reg, col=l&15.
__global__ __launch_bounds__(256, 2) void vq_screen(const unsigned short* __restrict__ zbf,
                                                    const unsigned short* __restrict__ wbf,
                                                    const float* __restrict__ Cn,
                                                    int* __restrict__ idx_out,
                                                    int* __restrict__ flagged,
                                                    int* __restrict__ cnt) {
    __shared__ unsigned short zT[128 * 64];
    __shared__ unsigned short wT[128 * 64];
    __shared__ float Cs[1024];
    __shared__ float rm1s[2][128];
    __shared__ float rm2s[2][128];
    __shared__ int   ris[2][128];

    const int t    = threadIdx.x;
    const int wv   = t >> 6;          // wave 0..3
    const int l    = t & 63;
    const int wm   = wv >> 1;         // row half
    const int wn   = wv & 1;          // col half
    const int m    = l & 15;
    const int quad = l >> 4;
    const int row0 = blockIdx.x * 128;

    for (int i = t; i < 1024; i += 256) Cs[i] = Cn[i];

    float m1[4][4], m2[4][4];
    int   bi[4][4];
    #pragma unroll
    for (int mi = 0; mi < 4; ++mi)
        #pragma unroll
        for (int r = 0; r < 4; ++r) { m1[mi][r] = FLT_MAX; m2[mi][r] = FLT_MAX; bi[mi][r] = 0; }

    const int sr  = t & 127;          // staging row
    const int ssw = sr & 7;           // staging swizzle

    for (int nb = 0; nb < 8; ++nb) {
        f32x4 acc[4][4];
        #pragma unroll
        for (int mi = 0; mi < 4; ++mi)
            #pragma unroll
            for (int ni = 0; ni < 4; ++ni) acc[mi][ni] = (f32x4){0.f, 0.f, 0.f, 0.f};

        for (int ks = 0; ks < 4; ++ks) {
            __syncthreads();
            {
                const unsigned short* src = (t < 128)
                    ? zbf + ((size_t)(row0 + sr) * D + ks * 64)
                    : wbf + ((size_t)(nb * 128 + sr) * D + ks * 64);
                unsigned short* dst = (t < 128) ? &zT[sr * 64] : &wT[sr * 64];
                #pragma unroll
                for (int c = 0; c < 8; ++c) {
                    uint4 v = *(const uint4*)(src + c * 8);
                    *(uint4*)(dst + ((c ^ ssw) * 8)) = v;
                }
            }
            __syncthreads();
            #pragma unroll
            for (int kk = 0; kk < 2; ++kk) {
                short8 a[4], b[4];
                const int ch = kk * 4 + quad;
                #pragma unroll
                for (int mi = 0; mi < 4; ++mi) {
                    const int rr = wm * 64 + mi * 16 + m;
                    a[mi] = *(const short8*)&zT[rr * 64 + ((ch ^ (m & 7)) * 8)];
                }
                #pragma unroll
                for (int ni = 0; ni < 4; ++ni) {
                    const int rr = wn * 64 + ni * 16 + m;
                    b[ni] = *(const short8*)&wT[rr * 64 + ((ch ^ (m & 7)) * 8)];
                }
                #pragma unroll
                for (int mi = 0; mi < 4; ++mi)
                    #pragma unroll
                    for (int ni = 0; ni < 4; ++ni)
                        acc[mi][ni] = __builtin_amdgcn_mfma_f32_16x16x32_bf16(
                            a[mi], b[ni], acc[mi][ni], 0, 0, 0);
            }
        }
        // epilogue for this n-block: v = C - 2B ; update per-lane (min1,min2,idx)
        #pragma unroll
        for (int ni = 0; ni < 4; ++ni) {
            const int code = nb * 128 + wn * 64 + ni * 16 + m;
            const float c  = Cs[code];
            #pragma unroll
            for (int mi = 0; mi < 4; ++mi)
                #pragma unroll
                for (int r = 0; r < 4; ++r) {
                    const float v = fmaf(-2.0f, acc[mi][ni][r], c);
                    if (v < m1[mi][r]) { m2[mi][r] = m1[mi][r]; m1[mi][r] = v; bi[mi][r] = code; }
                    else if (v < m2[mi][r]) m2[mi][r] = v;
                }
        }
    }

    // reduce across the 16 col-lanes (xor 1,2,4,8 varies l&15 only).
    // screen ties need no idx tie-break: equal mins -> margin 0 -> flagged -> exact.
    #pragma unroll
    for (int mi = 0; mi < 4; ++mi)
        #pragma unroll
        for (int r = 0; r < 4; ++r) {
            float a1 = m1[mi][r], a2 = m2[mi][r];
            int   ai = bi[mi][r];
            #pragma unroll
            for (int off = 1; off <= 8; off <<= 1) {
                float o1 = __shfl_xor(a1, off, 64);
                float o2 = __shfl_xor(a2, off, 64);
                int   oi = __shfl_xor(ai, off, 64);
                float n2 = fminf(a2, o2);
                if (o1 < a1) { n2 = fminf(n2, a1); a1 = o1; ai = oi; }
                else n2 = fminf(n2, o1);
                a2 = n2;
            }
            m1[mi][r] = a1; m2[mi][r] = a2; bi[mi][r] = ai;
        }

    if (m == 0) {
        #pragma unroll
        for (int mi = 0; mi < 4; ++mi)
            #pragma unroll
            for (int r = 0; r < 4; ++r) {
                const int rl = wm * 64 + mi * 16 + quad * 4 + r;
                rm1s[wn][rl] = m1[mi][r];
                rm2s[wn][rl] = m2[mi][r];
                ris[wn][rl]  = bi[mi][r];
            }
    }
    __syncthreads();
    if (t < 128) {
        float a1 = rm1s[0][t], a2 = rm2s[0][t];
        int   ai = ris[0][t];
        const float o1 = rm1s[1][t], o2 = rm2s[1][t];
        const int   oi = ris[1][t];
        float n2 = fminf(a2, o2);
        if (o1 < a1) { n2 = fminf(n2, a1); a1 = o1; ai = oi; }
        else n2 = fminf(n2, o1);
        a2 = n2;
        const int row = row0 + t;
        idx_out[row] = ai;
        if (a2 - a1 < TAU_SCREEN) {
            int p = atomicAdd(cnt, 1);
            flagged[p] = row;
        }
    }
}

// ---------------- exact numpy-sim refine (proven, round 3) ----------------
constexpr int RB = 8;
constexpr int CC = 32;
constexpr int LSTR = 260;

__global__ __launch_bounds__(256) void vq_refine(const float* __restrict__ z,
                                                 const float* __restrict__ w,
                                                 const float* __restrict__ Cn,
                                                 const int* __restrict__ flagged,
                                                 const int* __restrict__ cnt,
                                                 int* __restrict__ idx_out) {
    __shared__ float zl[RB][LSTR];
    __shared__ float wl[CC][LSTR];
    __shared__ float sA[RB];
    __shared__ int   rowids[RB];
    __shared__ float bestd[256];
    __shared__ int   besti[256];

    const int t  = threadIdx.x;
    const int cw = t >> 3;
    const int rw = t & 7;
    const int n  = *cnt;
    const int nbatch = (n + RB - 1) / RB;

    for (int batch = blockIdx.x; batch < nbatch; batch += gridDim.x) {
        __syncthreads();
        if (t < RB) {
            const int fi = batch * RB + t;
            rowids[t] = (fi < n) ? flagged[fi] : -1;
        }
        __syncthreads();
        for (int i = t; i < RB * 64; i += 256) {
            const int r = i >> 6, k4 = i & 63;
            const int row = rowids[r];
            float4 v = make_float4(0.f, 0.f, 0.f, 0.f);
            if (row >= 0) v = ((const float4*)(z + (size_t)row * D))[k4];
            *(float4*)&zl[r][k4 * 4] = v;
        }
        __syncthreads();
        if (t < RB) sA[t] = np_pairwise_sq256(zl[t]);

        float bd = FLT_MAX;
        int   bi = 0;
        for (int cc0 = 0; cc0 < CODES; cc0 += CC) {
            __syncthreads();
            for (int i = t; i < CC * 64; i += 256) {
                const int c = i >> 6, k4 = i & 63;
                *(float4*)&wl[c][k4 * 4] = ((const float4*)(w + (size_t)(cc0 + c) * D))[k4];
            }
            __syncthreads();
            float B = 0.f;
            #pragma unroll 4
            for (int k4 = 0; k4 < 64; ++k4) {
                float4 zv = *(const float4*)&zl[rw][k4 * 4];
                float4 wv = *(const float4*)&wl[cw][k4 * 4];
                B = fmaf(zv.x, wv.x, B);
                B = fmaf(zv.y, wv.y, B);
                B = fmaf(zv.z, wv.z, B);
                B = fmaf(zv.w, wv.w, B);
            }
            const int code = cc0 + cw;
            const float tt = __fsub_rn(sA[rw], __fmul_rn(2.0f, B));
            const float d  = __fadd_rn(tt, Cn[code]);
            if (d < bd || (d == bd && code < bi)) { bd = d; bi = code; }
        }
        bestd[t] = bd; besti[t] = bi;
        __syncthreads();
        for (int off = 128; off >= 8; off >>= 1) {
            if (t < off) {
                const float od = bestd[t + off];
                const int   oi = besti[t + off];
                if (od < bestd[t] || (od == bestd[t] && oi < besti[t])) {
                    bestd[t] = od; besti[t] = oi;
                }
            }
            __syncthreads();
        }
        if (t < RB) {
            const int row = rowids[t];
            if (row >= 0) idx_out[row] = besti[t];
        }
    }
}

// ---------------- gather ----------------
__global__ __launch_bounds__(256) void vq_gather(const float* __restrict__ w,
                                                 const int* __restrict__ idx,
                                                 float* __restrict__ outq,
                                                 float* __restrict__ outi) {
    const int t    = threadIdx.x;
    const int lane = t & 63;
    const int sub  = t >> 6;
    const int row0 = blockIdx.x * 128;
    #pragma unroll 4
    for (int it = 0; it < 32; ++it) {
        const int row = row0 + it * 4 + sub;
        const int j   = idx[row];
        ((float4*)outq)[(size_t)row * 64 + lane] = ((const float4*)w)[(size_t)j * 64 + lane];
        if (lane == 0) outi[row] = (float)j;
    }
}

extern "C" void kernel_launch(void* const* d_in, const int* in_sizes, int n_in,
                              void* d_out, int out_size, void* d_ws, size_t ws_size,
                              hipStream_t stream) {
    const float* z = (const float*)d_in[0];
    const float* w = (const float*)d_in[1];
    float* outq = (float*)d_out;
    float* outi = outq + (size_t)NROWS * D;

    // scratch inside d_out (dead before vq_gather overwrites it):
    //   zbf [0, 32MB) | wbf [32MB, +512KB) | Cn [+4KB)
    unsigned short* zbf = (unsigned short*)d_out;
    unsigned short* wbf = (unsigned short*)((char*)d_out + 33554432);
    float*          Cn  = (float*)((char*)d_out + 34078720);

    char* ws      = (char*)d_ws;
    int*  idx     = (int*)ws;
    int*  flagged = (int*)(ws + 262144);
    int*  cnt     = (int*)(ws + 524288);

    init_ws<<<1, 64, 0, stream>>>(cnt);
    to_bf16<<<NROWS * D / 8 / 256, 256, 0, stream>>>(z, zbf, NROWS * D / 8);
    to_bf16<<<CODES * D / 8 / 256, 256, 0, stream>>>(w, wbf, CODES * D / 8);
    rownorm_np<<<(CODES + 255) / 256, 256, 0, stream>>>(w, Cn, CODES);
    vq_screen<<<NROWS / 128, 256, 0, stream>>>(zbf, wbf, Cn, idx, flagged, cnt);
    vq_refine<<<512, 256, 0, stream>>>(z, w, Cn, flagged, cnt, idx);
    vq_gather<<<NROWS / 128, 256, 0, stream>>>(w, idx, outq, outi);
}